// Round 1
// baseline (141.232 us; speedup 1.0000x reference)
//
#include <hip/hip_runtime.h>
#include <stdint.h>

#define M_DIM 4096
#define K_DIM 256

typedef __attribute__((ext_vector_type(8))) short bf16x8;
typedef __attribute__((ext_vector_type(4))) float f32x4;

static __device__ __forceinline__ float bf2f(unsigned short u){
  unsigned int x = ((unsigned int)u) << 16; float f;
  __builtin_memcpy(&f, &x, 4); return f;
}
static __device__ __forceinline__ unsigned short f2bf(float f){
  unsigned int x; __builtin_memcpy(&x, &f, 4);
  unsigned int r = x + 0x7fffu + ((x >> 16) & 1u);
  return (unsigned short)(r >> 16);
}
static __device__ __forceinline__ void gld16(const void* g, void* l){
  __builtin_amdgcn_global_load_lds(
      (const __attribute__((address_space(1))) unsigned int*)g,
      (__attribute__((address_space(3))) unsigned int*)l, 16, 0, 0);
}

// ---------------- transpose [b,256,4096] f32 -> [b,4096,256] bf16 (K-contiguous) ----
__global__ void k_transpose_cast(const float* __restrict__ in,
                                 unsigned short* __restrict__ out, float scale){
  __shared__ float lds[64][65];
  int b = blockIdx.z, c0 = blockIdx.y * 64, m0 = blockIdx.x * 64;
  const float* ib = in + (size_t)b * K_DIM * M_DIM;
  unsigned short* ob = out + (size_t)b * M_DIM * K_DIM;
  int t = threadIdx.x, r = t >> 6, j = t & 63;
#pragma unroll
  for (int k = 0; k < 16; k++)
    lds[r + k*4][j] = ib[(size_t)(c0 + r + k*4) * M_DIM + m0 + j];
  __syncthreads();
#pragma unroll
  for (int k = 0; k < 16; k++)
    ob[(size_t)(m0 + r + k*4) * K_DIM + c0 + j] = f2bf(lds[j][r + k*4] * scale);
}

// ---------------- 2x2 mean pool of B over fmap2 spatial dims ------------------------
// src: [b, (2wd)*(2wd), 256] bf16 ; dst: [b, wd*wd, 256]
__global__ void k_pool(const unsigned short* __restrict__ src,
                       unsigned short* __restrict__ dst, int wd){
  int t = threadIdx.x;
  int idx = blockIdx.x * 4 + (t >> 6);
  int l = t & 63;
  int per = wd * wd;
  int b = idx / per, rem = idx - b * per;
  int y = rem / wd, x = rem - y * wd;
  int ws2 = wd * 2;
  const unsigned short* sb = src + (size_t)b * per * 4 * K_DIM;
  unsigned short* db = dst + (size_t)b * per * K_DIM;
  int c = l * 4;
  size_t r00 = ((size_t)(2*y) * ws2 + 2*x) * K_DIM + c;
  size_t r01 = r00 + K_DIM;
  size_t r10 = r00 + (size_t)ws2 * K_DIM;
  size_t r11 = r10 + K_DIM;
  uint2 va = *(const uint2*)(sb + r00);
  uint2 vb = *(const uint2*)(sb + r01);
  uint2 vc = *(const uint2*)(sb + r10);
  uint2 vd = *(const uint2*)(sb + r11);
  float s0 = (bf2f(va.x & 0xffff) + bf2f(vb.x & 0xffff) + bf2f(vc.x & 0xffff) + bf2f(vd.x & 0xffff)) * 0.25f;
  float s1 = (bf2f(va.x >> 16)  + bf2f(vb.x >> 16)  + bf2f(vc.x >> 16)  + bf2f(vd.x >> 16))  * 0.25f;
  float s2 = (bf2f(va.y & 0xffff) + bf2f(vb.y & 0xffff) + bf2f(vc.y & 0xffff) + bf2f(vd.y & 0xffff)) * 0.25f;
  float s3 = (bf2f(va.y >> 16)  + bf2f(vb.y >> 16)  + bf2f(vc.y >> 16)  + bf2f(vd.y >> 16))  * 0.25f;
  uint2 o;
  o.x = (unsigned)f2bf(s0) | ((unsigned)f2bf(s1) << 16);
  o.y = (unsigned)f2bf(s2) | ((unsigned)f2bf(s3) << 16);
  *(uint2*)(db + (size_t)rem * K_DIM + c) = o;
}

// ---------------- GEMM: C[m,n] = sum_c A[m,c]*B[n,c]  (both K-contiguous, bf16) -----
// 128x128 tile, BK=32, 4 waves (2x2 of 64x64), mfma_f32_16x16x32_bf16
__global__ void k_gemm(const unsigned short* __restrict__ A,
                       const unsigned short* __restrict__ B,
                       unsigned short* __restrict__ C, int N){
  __shared__ __align__(16) unsigned short As[128 * 32];
  __shared__ __align__(16) unsigned short Bs[128 * 32];
  int b = blockIdx.z;
  const unsigned short* Ab = A + (size_t)b * M_DIM * K_DIM;
  const unsigned short* Bb = B + (size_t)b * N * K_DIM;
  unsigned short* Cb = C + (size_t)b * M_DIM * N;
  int m0 = blockIdx.y * 128, n0 = blockIdx.x * 128;
  int t = threadIdx.x;
  int wave = t >> 6, lane = t & 63;
  int wm = (wave >> 1) * 64, wn = (wave & 1) * 64;
  int srow = t >> 2, scol = (t & 3) * 8;
  int fr = lane & 15, fk = (lane >> 4) * 8;
  f32x4 acc[4][4];
#pragma unroll
  for (int i = 0; i < 4; i++)
#pragma unroll
    for (int j = 0; j < 4; j++) acc[i][j] = (f32x4){0.f, 0.f, 0.f, 0.f};

  int nr0 = n0 + srow;      if (nr0 > N - 1) nr0 = N - 1;
  int nr1 = n0 + srow + 64; if (nr1 > N - 1) nr1 = N - 1;
  const unsigned short* ga0 = Ab + (size_t)(m0 + srow) * K_DIM + scol;
  const unsigned short* ga1 = Ab + (size_t)(m0 + srow + 64) * K_DIM + scol;
  const unsigned short* gb0 = Bb + (size_t)nr0 * K_DIM + scol;
  const unsigned short* gb1 = Bb + (size_t)nr1 * K_DIM + scol;

  for (int kt = 0; kt < K_DIM; kt += 32){
    __syncthreads();
    gld16(ga0 + kt, (unsigned short*)As + t * 8);
    gld16(ga1 + kt, (unsigned short*)As + t * 8 + 2048);
    gld16(gb0 + kt, (unsigned short*)Bs + t * 8);
    gld16(gb1 + kt, (unsigned short*)Bs + t * 8 + 2048);
    asm volatile("s_waitcnt vmcnt(0)" ::: "memory");
    __syncthreads();
    bf16x8 af[4], bfv[4];
#pragma unroll
    for (int i = 0; i < 4; i++)
      af[i] = *(const bf16x8*)((unsigned short*)As + (wm + i*16 + fr) * 32 + fk);
#pragma unroll
    for (int j = 0; j < 4; j++)
      bfv[j] = *(const bf16x8*)((unsigned short*)Bs + (wn + j*16 + fr) * 32 + fk);
#pragma unroll
    for (int i = 0; i < 4; i++)
#pragma unroll
      for (int j = 0; j < 4; j++)
        acc[i][j] = __builtin_amdgcn_mfma_f32_16x16x32_bf16(af[i], bfv[j], acc[i][j], 0, 0, 0);
  }

  int cr = (lane >> 4) * 4, ccol = lane & 15;
#pragma unroll
  for (int i = 0; i < 4; i++){
#pragma unroll
    for (int j = 0; j < 4; j++){
      int col = n0 + wn + j*16 + ccol;
      if (col < N){
        size_t base = (size_t)(m0 + wm + i*16 + cr) * N + col;
#pragma unroll
        for (int r = 0; r < 4; r++)
          Cb[base + (size_t)r * N] = f2bf(acc[i][j][r]);
      }
    }
  }
}

// ---------------- sampler: bilinear 9x9 windows at 4 levels ------------------------
__global__ void k_sample(const unsigned short* __restrict__ p0,
                         const unsigned short* __restrict__ p1,
                         const unsigned short* __restrict__ p2,
                         const unsigned short* __restrict__ p3,
                         const float* __restrict__ cc, float* __restrict__ out){
  int i = blockIdx.x, b = blockIdx.y, lvl = blockIdx.z;
  int j = threadIdx.x;
  const unsigned short* corr; int wl;
  if (lvl == 0)      { corr = p0; wl = 64; }
  else if (lvl == 1) { corr = p1; wl = 32; }
  else if (lvl == 2) { corr = p2; wl = 16; }
  else               { corr = p3; wl = 8;  }
  float inv = 1.0f / (float)(1 << lvl);
  int m = i * 64 + j;
  const unsigned short* rowp = corr + (size_t)(b * M_DIM + m) * (wl * wl);
  float cx = cc[((size_t)(b*2 + 0) * 64 + i) * 64 + j];
  float cy = cc[((size_t)(b*2 + 1) * 64 + i) * 64 + j];
  float x = cx * inv, y = cy * inv;
  float x0f = floorf(x), y0f = floorf(y);
  int x0 = (int)x0f, y0 = (int)y0f;
  float fx = x - x0f, fy = y - y0f;
  float C[10][10];
#pragma unroll
  for (int v = 0; v < 10; v++){
    int ry = y0 - 4 + v;
    bool vy = (unsigned)ry < (unsigned)wl;
    int ryc = ry < 0 ? 0 : (ry > wl - 1 ? wl - 1 : ry);
#pragma unroll
    for (int u = 0; u < 10; u++){
      int rx = x0 - 4 + u;
      bool vx = (unsigned)rx < (unsigned)wl;
      int rxc = rx < 0 ? 0 : (rx > wl - 1 ? wl - 1 : rx);
      float val = bf2f(rowp[ryc * wl + rxc]);
      C[v][u] = (vx && vy) ? val : 0.0f;
    }
  }
  float wx1 = fx, wx0 = 1.0f - fx, wy1 = fy, wy0 = 1.0f - fy;
  size_t obase = (size_t)b * 324 + lvl * 81;
#pragma unroll
  for (int a = 0; a < 9; a++){
#pragma unroll
    for (int d = 0; d < 9; d++){
      float val = wy0 * (wx0 * C[d][a]   + wx1 * C[d][a+1])
                + wy1 * (wx0 * C[d+1][a] + wx1 * C[d+1][a+1]);
      out[((obase + a*9 + d) * 64 + i) * 64 + j] = val;
    }
  }
}

extern "C" void kernel_launch(void* const* d_in, const int* in_sizes, int n_in,
                              void* d_out, int out_size, void* d_ws, size_t ws_size,
                              hipStream_t stream){
  (void)in_sizes; (void)n_in; (void)out_size; (void)ws_size;
  const float* f1 = (const float*)d_in[0];
  const float* f2 = (const float*)d_in[1];
  const float* cc = (const float*)d_in[2];
  float* out = (float*)d_out;
  char* ws = (char*)d_ws;
  // workspace layout (bytes)
  unsigned short* A  = (unsigned short*)(ws + 0);          //  4 MB  f1^T bf16 (scaled 1/16)
  unsigned short* B0 = (unsigned short*)(ws + 4194304);    //  4 MB  f2^T bf16
  unsigned short* B1 = (unsigned short*)(ws + 8388608);    //  1 MB
  unsigned short* B2 = (unsigned short*)(ws + 9437184);    //  256 KB
  unsigned short* B3 = (unsigned short*)(ws + 9699328);    //  64 KB
  unsigned short* C0 = (unsigned short*)(ws + 9764864);    //  64 MB corr level 0
  unsigned short* C1 = (unsigned short*)(ws + 76873728);   //  16 MB
  unsigned short* C2 = (unsigned short*)(ws + 93650944);   //  4 MB
  unsigned short* C3 = (unsigned short*)(ws + 97845248);   //  1 MB   (total ~94.3 MB)

  dim3 bt(256);
  k_transpose_cast<<<dim3(64, 4, 2), bt, 0, stream>>>(f1, A, 0.0625f);
  k_transpose_cast<<<dim3(64, 4, 2), bt, 0, stream>>>(f2, B0, 1.0f);
  k_pool<<<dim3(512), bt, 0, stream>>>(B0, B1, 32);
  k_pool<<<dim3(128), bt, 0, stream>>>(B1, B2, 16);
  k_pool<<<dim3(32),  bt, 0, stream>>>(B2, B3, 8);
  k_gemm<<<dim3(32, 32, 2), bt, 0, stream>>>(A, B0, C0, 4096);
  k_gemm<<<dim3(8, 32, 2),  bt, 0, stream>>>(A, B1, C1, 1024);
  k_gemm<<<dim3(2, 32, 2),  bt, 0, stream>>>(A, B2, C2, 256);
  k_gemm<<<dim3(1, 32, 2),  bt, 0, stream>>>(A, B3, C3, 64);
  k_sample<<<dim3(64, 2, 4), dim3(64), 0, stream>>>(C0, C1, C2, C3, cc, out);
}